// Round 9
// baseline (167.926 us; speedup 1.0000x reference)
//
#include <hip/hip_runtime.h>
#include <math.h>

#define BB 8
#define NN 4096
#define MM 4000
#define KK 5
#define NWAVE 8
#define QPB 64                        // queries per block (1 per lane)
#define CH 512                        // candidates per wave-chunk
#define NTILE (CH / 64)               // 8 tiles of 64
#define NPAD 4096
#define SCAN_BLOCKS ((NN / QPB) * BB * 2)   // 64*8*2 = 1024

#define ACC_ROT    0
#define ACC_TRANS  1
#define ACC_ALIGN  2
#define ACC_DISP   3
#define ACC_DEFORM 4
#define ACC_LAP    5
#define ACC_RMSE   6   // 8 entries
#define ACC_COUNT  14

#define INFF __int_as_float(0x7F800000)

__device__ __forceinline__ float waveReduceSum(float v) {
#pragma unroll
    for (int off = 32; off > 0; off >>= 1) v += __shfl_down(v, off, 64);
    return v;
}

__device__ __forceinline__ float rlane(float v, int l) {
    return __int_as_float(__builtin_amdgcn_readlane(__float_as_int(v), l));
}

// Scan a CH-candidate chunk held per-lane in registers. Inner loop: broadcast
// lane j's candidate via v_readlane (VALU pipe, no DS/SMEM), score against
// the lane's own query (score shifted by -|q|^2, ranking-invariant), insert
// into sorted top-5 via 1 min + 4 independent med3. PACK: candidate index in
// low 12 mantissa bits (tie -> smaller index, = top_k). Zero memory ops per
// candidate; next tile's global load prefetched under ~900 VALU instrs.
template<bool SELF, bool PACK>
__device__ __forceinline__ void scanReg(const float4* __restrict__ cb, int tc,
                                        float ca, float cbq, float cc, int q,
                                        int lane,
                                        float& b0, float& b1, float& b2,
                                        float& b3, float& b4) {
    float4 cur = cb[tc + lane];
    for (int t = 0; t < NTILE; ++t) {
        float4 nxt = cur;
        if (t + 1 < NTILE) nxt = cb[tc + (t + 1) * 64 + lane];
        int mbase = tc + t * 64;
#pragma unroll
        for (int j = 0; j < 64; ++j) {
            float cx = rlane(cur.x, j), cy = rlane(cur.y, j);
            float cz = rlane(cur.z, j), cw = rlane(cur.w, j);
            float sc = fmaf(cx, ca, fmaf(cy, cbq, cz * cc + cw));
            float v;
            if (PACK) {
                unsigned pk = (__float_as_uint(sc) & 0xFFFFF000u) | (unsigned)(mbase + j);
                v = __uint_as_float(pk);
                if (SELF) v = (mbase + j == q) ? INFF : v;
            } else {
                v = sc;
            }
            float n0 = fminf(b0, v);
            float n1 = __builtin_amdgcn_fmed3f(v, b0, b1);
            float n2 = __builtin_amdgcn_fmed3f(v, b1, b2);
            float n3 = __builtin_amdgcn_fmed3f(v, b2, b3);
            float n4 = __builtin_amdgcn_fmed3f(v, b3, b4);
            b0 = n0; b1 = n1; b2 = n2; b3 = n3; b4 = n4;
        }
        cur = nxt;
    }
}

// K1: Y_rigid (padded float4 + norm), X padded float4 + norm, rmse/disp
// partials, rot/trans losses.
__global__ void k_prep(const float* __restrict__ Y, const float* __restrict__ X,
                       const float* __restrict__ Rp, const float* __restrict__ tp,
                       const float* __restrict__ Rg, const float* __restrict__ tg,
                       const float* __restrict__ dl,
                       float4* __restrict__ YrP, float4* __restrict__ XP,
                       float* __restrict__ acc) {
    int b = blockIdx.x >> 4;
    int n = ((blockIdx.x & 15) << 8) + threadIdx.x;
    size_t base = ((size_t)b * NN + n) * 3;
    float yx = Y[base + 0], yy = Y[base + 1], yz = Y[base + 2];

    float rp[9], rg[9], tpv[3], tgv[3];
#pragma unroll
    for (int i = 0; i < 9; ++i) { rp[i] = Rp[b * 9 + i]; rg[i] = Rg[b * 9 + i]; }
#pragma unroll
    for (int i = 0; i < 3; ++i) { tpv[i] = tp[b * 3 + i]; tgv[i] = tg[b * 3 + i]; }

    float p[3], dr2 = 0.f;
#pragma unroll
    for (int k = 0; k < 3; ++k) {
        float pv = fmaf(yx, rp[k * 3 + 0], fmaf(yy, rp[k * 3 + 1], fmaf(yz, rp[k * 3 + 2], tpv[k])));
        float gv = fmaf(yx, rg[k * 3 + 0], fmaf(yy, rg[k * 3 + 1], fmaf(yz, rg[k * 3 + 2], tgv[k])));
        p[k] = pv;
        float dd = pv - gv;
        dr2 = fmaf(dd, dd, dr2);
    }
    YrP[(size_t)b * NPAD + n] =
        make_float4(p[0], p[1], p[2], fmaf(p[0], p[0], fmaf(p[1], p[1], p[2] * p[2])));

    float4 xe;
    if (n < MM) {
        size_t xb = ((size_t)b * MM + n) * 3;
        float x0 = X[xb + 0], x1 = X[xb + 1], x2 = X[xb + 2];
        xe = make_float4(x0, x1, x2, fmaf(x0, x0, fmaf(x1, x1, x2 * x2)));
    } else {
        xe = make_float4(0.f, 0.f, 0.f, INFF);
    }
    XP[(size_t)b * NPAD + n] = xe;

    float d0 = dl[base + 0], d1 = dl[base + 1], d2 = dl[base + 2];
    float dsq = d0 * d0 + d1 * d1 + d2 * d2;

    dr2 = waveReduceSum(dr2);
    dsq = waveReduceSum(dsq);
    if ((threadIdx.x & 63) == 0) {
        atomicAdd(&acc[ACC_RMSE + b], dr2);
        atomicAdd(&acc[ACC_DISP], dsq);
    }

    if (threadIdx.x == 0 && (blockIdx.x & 15) == 0) {
        float tr = 0.f;
#pragma unroll
        for (int i = 0; i < 9; ++i) tr += rp[i] * rg[i];
        float c = (tr - 1.f) * 0.5f;
        c = fminf(fmaxf(c, -1.f + 1e-7f), 1.f - 1e-7f);
        float dx = tpv[0] - tgv[0], dy = tpv[1] - tgv[1], dz = tpv[2] - tgv[2];
        atomicAdd(&acc[ACC_ROT], acosf(c));
        atomicAdd(&acc[ACC_TRANS], sqrtf(dx * dx + dy * dy + dz * dz));
    }
}

__device__ void finalize(const float* acc, float* out) {
    float a[ACC_COUNT];
#pragma unroll
    for (int i = 0; i < ACC_COUNT; ++i)
        a[i] = __hip_atomic_load(&acc[i], __ATOMIC_RELAXED, __HIP_MEMORY_SCOPE_AGENT);
    float L_rot = a[ACC_ROT] / BB;
    float L_trans = a[ACC_TRANS] / BB;
    float L_rmse = 0.f;
#pragma unroll
    for (int b = 0; b < BB; ++b) L_rmse += sqrtf(a[ACC_RMSE + b] / NN);
    L_rmse /= BB;
    float L_align = a[ACC_ALIGN] / ((float)BB * NN * KK);
    float L_disp = a[ACC_DISP] / ((float)BB * NN);
    float L_def = a[ACC_DEFORM] / ((float)BB * NN * KK);
    float L_lap = a[ACC_LAP] / ((float)BB * NN);
    float rigid = L_rot + L_trans + L_rmse;
    float nr = L_align + 0.01f * L_disp + 0.1f * L_def + 0.1f * L_lap;
    out[0] = rigid + nr; out[1] = rigid; out[2] = nr;
    out[3] = L_rot; out[4] = L_trans; out[5] = L_rmse;
    out[6] = L_align; out[7] = L_disp; out[8] = L_def; out[9] = L_lap;
}

#define MERGE_STEP(W) { float d = md[W][l][pp##W]; if (d < best) { best = d; bw = W; } }
#define MERGE_ADV()  { pp0 += (bw == 0); pp1 += (bw == 1); pp2 += (bw == 2); pp3 += (bw == 3); \
                       pp4 += (bw == 4); pp5 += (bw == 5); pp6 += (bw == 6); pp7 += (bw == 7); }

// K2: fused scan, register-resident candidates + v_readlane broadcast.
// blockIdx.z = mode (0=align on XP, 1=knn on YrP). 8 waves x 512-candidate
// chunks; in-block 8-way merge -> loss terms -> last-block finalize.
__global__ __launch_bounds__(512, 8) void k_scan(const float* __restrict__ Xh,
                                                 const float4* __restrict__ XP,
                                                 const float4* __restrict__ YrP,
                                                 const float* __restrict__ dl,
                                                 float* __restrict__ acc,
                                                 unsigned* __restrict__ doneCnt,
                                                 float* __restrict__ out) {
    __shared__ float md[NWAVE][QPB][6];            // 12 KB merge partials
    int tid = threadIdx.x, wave = tid >> 6, lane = tid & 63;
    int qg = blockIdx.x, b = blockIdx.y, mode = blockIdx.z;
    int q = qg * QPB + lane;

    const float4* cbG = (mode == 0 ? XP : YrP) + (size_t)b * NPAD;

    float qx, qy, qz, qn = 0.f;
    float4 qp;
    if (mode == 0) {
        size_t a0 = ((size_t)b * NN + q) * 3;
        qx = Xh[a0 + 0]; qy = Xh[a0 + 1]; qz = Xh[a0 + 2];
        qn = fmaf(qx, qx, fmaf(qy, qy, qz * qz));
    } else {
        qp = cbG[q];
        qx = qp.x; qy = qp.y; qz = qp.z;
    }

    float b0 = INFF, b1 = INFF, b2 = INFF, b3 = INFF, b4 = INFF;
    int tc = wave * CH;
    if (mode == 0) {
        scanReg<false, false>(cbG, tc, -2.f * qx, -2.f * qy, -2.f * qz, 0, lane,
                              b0, b1, b2, b3, b4);
    } else if (wave == (qg >> 3)) {                // chunk containing this block's queries
        scanReg<true, true>(cbG, tc, -2.f * qx, -2.f * qy, -2.f * qz, q, lane,
                            b0, b1, b2, b3, b4);
    } else {
        scanReg<false, true>(cbG, tc, -2.f * qx, -2.f * qy, -2.f * qz, q, lane,
                             b0, b1, b2, b3, b4);
    }

    md[wave][lane][0] = b0; md[wave][lane][1] = b1; md[wave][lane][2] = b2;
    md[wave][lane][3] = b3; md[wave][lane][4] = b4; md[wave][lane][5] = INFF;
    __syncthreads();

    if (tid < QPB) {                               // wave 0: its own q/qn/qp are valid
        int l = tid;
        int pp0 = 0, pp1 = 0, pp2 = 0, pp3 = 0, pp4 = 0, pp5 = 0, pp6 = 0, pp7 = 0;
        if (mode == 0) {
            float s = 0.f;
#pragma unroll
            for (int k = 0; k < KK; ++k) {
                float best = INFF; int bw = 0;
                MERGE_STEP(0) MERGE_STEP(1) MERGE_STEP(2) MERGE_STEP(3)
                MERGE_STEP(4) MERGE_STEP(5) MERGE_STEP(6) MERGE_STEP(7)
                s += fmaxf(best + qn, 0.f);
                MERGE_ADV()
            }
            s = waveReduceSum(s);
            if (l == 0) atomicAdd(&acc[ACC_ALIGN], s);
        } else {
            int si[KK];
#pragma unroll
            for (int k = 0; k < KK; ++k) {
                float best = INFF; int bw = 0;
                MERGE_STEP(0) MERGE_STEP(1) MERGE_STEP(2) MERGE_STEP(3)
                MERGE_STEP(4) MERGE_STEP(5) MERGE_STEP(6) MERGE_STEP(7)
                si[k] = (int)(__float_as_uint(best) & 0xFFFu);
                MERGE_ADV()
            }
            const float* xh = Xh + (size_t)b * NN * 3;
            const float* dlb = dl + (size_t)b * NN * 3;
            float xnx = xh[q * 3 + 0], xny = xh[q * 3 + 1], xnz = xh[q * 3 + 2];
            float dnx = dlb[q * 3 + 0], dny = dlb[q * 3 + 1], dnz = dlb[q * 3 + 2];

            float def = 0.f, sx = 0.f, sy = 0.f, sz = 0.f;
#pragma unroll
            for (int k = 0; k < KK; ++k) {
                int n = si[k];
                float4 yj = cbG[n];                // gather from L2-resident buffer
                float ex = (xh[n * 3 + 0] - xnx) - (yj.x - qp.x);
                float ey = (xh[n * 3 + 1] - xny) - (yj.y - qp.y);
                float ez = (xh[n * 3 + 2] - xnz) - (yj.z - qp.z);
                def += ex * ex + ey * ey + ez * ez;
                sx += dlb[n * 3 + 0]; sy += dlb[n * 3 + 1]; sz += dlb[n * 3 + 2];
            }
            float lx = dnx - sx / 5.f, ly = dny - sy / 5.f, lz = dnz - sz / 5.f;
            float lap = lx * lx + ly * ly + lz * lz;

            def = waveReduceSum(def);
            lap = waveReduceSum(lap);
            if (l == 0) {
                atomicAdd(&acc[ACC_DEFORM], def);
                atomicAdd(&acc[ACC_LAP], lap);
            }
        }
    }
    __syncthreads();
    if (tid == 0) {
        __threadfence();
        unsigned t = __hip_atomic_fetch_add(doneCnt, 1u, __ATOMIC_ACQ_REL,
                                            __HIP_MEMORY_SCOPE_AGENT);
        if (t == SCAN_BLOCKS - 1) finalize(acc, out);
    }
}

extern "C" void kernel_launch(void* const* d_in, const int* in_sizes, int n_in,
                              void* d_out, int out_size, void* d_ws, size_t ws_size,
                              hipStream_t stream) {
    const float* Y  = (const float*)d_in[0];
    const float* X  = (const float*)d_in[1];
    const float* Rp = (const float*)d_in[2];
    const float* tp = (const float*)d_in[3];
    const float* Rg = (const float*)d_in[4];
    const float* tg = (const float*)d_in[5];
    const float* Xh = (const float*)d_in[6];
    const float* dl = (const float*)d_in[7];
    float* out = (float*)d_out;

    float*    acc     = (float*)d_ws;                            // 14 floats
    unsigned* doneCnt = (unsigned*)((char*)d_ws + 64);
    float4*   YrP     = (float4*)((char*)d_ws + 512);            // 512 KB
    float4*   XP      = YrP + (size_t)BB * NPAD;                 // 512 KB

    hipMemsetAsync(d_ws, 0, 512, stream);
    hipLaunchKernelGGL(k_prep, dim3(BB * NN / 256), dim3(256), 0, stream,
                       Y, X, Rp, tp, Rg, tg, dl, YrP, XP, acc);
    hipLaunchKernelGGL(k_scan, dim3(NN / QPB, BB, 2), dim3(512), 0, stream,
                       Xh, XP, YrP, dl, acc, doneCnt, out);
}

// Round 10
// 109.731 us; speedup vs baseline: 1.5303x; 1.5303x over previous
//
#include <hip/hip_runtime.h>
#include <math.h>

#define BB 8
#define NN 4096
#define MM 4000
#define KK 5
#define NWAVE 8
#define QG 128                        // queries per block (2 per lane)
#define CH 512                        // candidates per wave-chunk
#define NPAD 4096
#define SCAN_BLOCKS ((NN / QG) * BB * 2)   // 32*8*2 = 512

#define ACC_ROT    0
#define ACC_TRANS  1
#define ACC_ALIGN  2
#define ACC_DISP   3
#define ACC_DEFORM 4
#define ACC_LAP    5
#define ACC_RMSE   6   // 8 entries
#define ACC_COUNT  14

#define INFF __int_as_float(0x7F800000)

__device__ __forceinline__ float waveReduceSum(float v) {
#pragma unroll
    for (int off = 32; off > 0; off >>= 1) v += __shfl_down(v, off, 64);
    return v;
}

// Insert v into sorted (b0<=..<=b4): 1 min + 4 independent med3 (proven r6+).
// Score shifted by -|q|^2 (ranking-invariant). PACK: candidate index in low
// 12 mantissa bits (tie -> smaller index, = top_k semantics).
template<bool SELF, bool PACK>
__device__ __forceinline__ void proc1(float4 c, int midx, int q,
                                      float ca, float cbq, float cc,
                                      float& b0, float& b1, float& b2,
                                      float& b3, float& b4) {
    float sc = fmaf(c.x, ca, fmaf(c.y, cbq, fmaf(c.z, cc, c.w)));
    float v;
    if (PACK) {
        unsigned pk = (__float_as_uint(sc) & 0xFFFFF000u) | (unsigned)midx;
        v = __uint_as_float(pk);
        if (SELF) v = (midx == q) ? INFF : v;
    } else {
        v = sc;
    }
    float n0 = fminf(b0, v);
    float n1 = __builtin_amdgcn_fmed3f(v, b0, b1);
    float n2 = __builtin_amdgcn_fmed3f(v, b1, b2);
    float n3 = __builtin_amdgcn_fmed3f(v, b2, b3);
    float n4 = __builtin_amdgcn_fmed3f(v, b3, b4);
    b0 = n0; b1 = n1; b2 = n2; b3 = n3; b4 = n4;
}

// Scan a CH-candidate LDS chunk for TWO queries per lane. One broadcast
// ds_read_b128 serves 128 pairs -> DS-pipe pressure halved vs Q=1. 4-deep
// A/B ping-pong (32 VGPR) under the 128-reg cap; DS completes in order so
// partial lgkmcnt waits pipeline the reads.
template<bool SELF, bool PACK>
__device__ __forceinline__ void scanLDS2(const float4* lc, int tc,
                                         float a0, float b0c, float c0, int q0,
                                         float a1, float b1c, float c1, int q1,
                                         float& x0, float& x1, float& x2,
                                         float& x3, float& x4,
                                         float& y0, float& y1, float& y2,
                                         float& y3, float& y4) {
    float4 A[4], B[4];
#pragma unroll
    for (int j = 0; j < 4; ++j) A[j] = lc[tc + j];

    for (int t0 = 0; t0 < CH; t0 += 8) {
#pragma unroll
        for (int j = 0; j < 4; ++j) B[j] = lc[tc + t0 + 4 + j];
#pragma unroll
        for (int j = 0; j < 4; ++j) {
            proc1<SELF, PACK>(A[j], tc + t0 + j, q0, a0, b0c, c0, x0, x1, x2, x3, x4);
            proc1<SELF, PACK>(A[j], tc + t0 + j, q1, a1, b1c, c1, y0, y1, y2, y3, y4);
        }
        if (t0 + 8 < CH) {
#pragma unroll
            for (int j = 0; j < 4; ++j) A[j] = lc[tc + t0 + 8 + j];
        }
#pragma unroll
        for (int j = 0; j < 4; ++j) {
            proc1<SELF, PACK>(B[j], tc + t0 + 4 + j, q0, a0, b0c, c0, x0, x1, x2, x3, x4);
            proc1<SELF, PACK>(B[j], tc + t0 + 4 + j, q1, a1, b1c, c1, y0, y1, y2, y3, y4);
        }
    }
}

// K1: Y_rigid (padded float4 + norm), X padded float4 + norm, rmse/disp
// partials, rot/trans losses.
__global__ void k_prep(const float* __restrict__ Y, const float* __restrict__ X,
                       const float* __restrict__ Rp, const float* __restrict__ tp,
                       const float* __restrict__ Rg, const float* __restrict__ tg,
                       const float* __restrict__ dl,
                       float4* __restrict__ YrP, float4* __restrict__ XP,
                       float* __restrict__ acc) {
    int b = blockIdx.x >> 4;
    int n = ((blockIdx.x & 15) << 8) + threadIdx.x;
    size_t base = ((size_t)b * NN + n) * 3;
    float yx = Y[base + 0], yy = Y[base + 1], yz = Y[base + 2];

    float rp[9], rg[9], tpv[3], tgv[3];
#pragma unroll
    for (int i = 0; i < 9; ++i) { rp[i] = Rp[b * 9 + i]; rg[i] = Rg[b * 9 + i]; }
#pragma unroll
    for (int i = 0; i < 3; ++i) { tpv[i] = tp[b * 3 + i]; tgv[i] = tg[b * 3 + i]; }

    float p[3], dr2 = 0.f;
#pragma unroll
    for (int k = 0; k < 3; ++k) {
        float pv = fmaf(yx, rp[k * 3 + 0], fmaf(yy, rp[k * 3 + 1], fmaf(yz, rp[k * 3 + 2], tpv[k])));
        float gv = fmaf(yx, rg[k * 3 + 0], fmaf(yy, rg[k * 3 + 1], fmaf(yz, rg[k * 3 + 2], tgv[k])));
        p[k] = pv;
        float dd = pv - gv;
        dr2 = fmaf(dd, dd, dr2);
    }
    YrP[(size_t)b * NPAD + n] =
        make_float4(p[0], p[1], p[2], fmaf(p[0], p[0], fmaf(p[1], p[1], p[2] * p[2])));

    float4 xe;
    if (n < MM) {
        size_t xb = ((size_t)b * MM + n) * 3;
        float x0 = X[xb + 0], x1 = X[xb + 1], x2 = X[xb + 2];
        xe = make_float4(x0, x1, x2, fmaf(x0, x0, fmaf(x1, x1, x2 * x2)));
    } else {
        xe = make_float4(0.f, 0.f, 0.f, INFF);
    }
    XP[(size_t)b * NPAD + n] = xe;

    float d0 = dl[base + 0], d1 = dl[base + 1], d2 = dl[base + 2];
    float dsq = d0 * d0 + d1 * d1 + d2 * d2;

    dr2 = waveReduceSum(dr2);
    dsq = waveReduceSum(dsq);
    if ((threadIdx.x & 63) == 0) {
        atomicAdd(&acc[ACC_RMSE + b], dr2);
        atomicAdd(&acc[ACC_DISP], dsq);
    }

    if (threadIdx.x == 0 && (blockIdx.x & 15) == 0) {
        float tr = 0.f;
#pragma unroll
        for (int i = 0; i < 9; ++i) tr += rp[i] * rg[i];
        float c = (tr - 1.f) * 0.5f;
        c = fminf(fmaxf(c, -1.f + 1e-7f), 1.f - 1e-7f);
        float dx = tpv[0] - tgv[0], dy = tpv[1] - tgv[1], dz = tpv[2] - tgv[2];
        atomicAdd(&acc[ACC_ROT], acosf(c));
        atomicAdd(&acc[ACC_TRANS], sqrtf(dx * dx + dy * dy + dz * dz));
    }
}

__device__ void finalize(const float* acc, float* out) {
    float a[ACC_COUNT];
#pragma unroll
    for (int i = 0; i < ACC_COUNT; ++i)
        a[i] = __hip_atomic_load(&acc[i], __ATOMIC_RELAXED, __HIP_MEMORY_SCOPE_AGENT);
    float L_rot = a[ACC_ROT] / BB;
    float L_trans = a[ACC_TRANS] / BB;
    float L_rmse = 0.f;
#pragma unroll
    for (int b = 0; b < BB; ++b) L_rmse += sqrtf(a[ACC_RMSE + b] / NN);
    L_rmse /= BB;
    float L_align = a[ACC_ALIGN] / ((float)BB * NN * KK);
    float L_disp = a[ACC_DISP] / ((float)BB * NN);
    float L_def = a[ACC_DEFORM] / ((float)BB * NN * KK);
    float L_lap = a[ACC_LAP] / ((float)BB * NN);
    float rigid = L_rot + L_trans + L_rmse;
    float nr = L_align + 0.01f * L_disp + 0.1f * L_def + 0.1f * L_lap;
    out[0] = rigid + nr; out[1] = rigid; out[2] = nr;
    out[3] = L_rot; out[4] = L_trans; out[5] = L_rmse;
    out[6] = L_align; out[7] = L_disp; out[8] = L_def; out[9] = L_lap;
}

#define MERGE_STEP(W) { float d = mdp[((W) * QG + l) * 6 + pp##W]; if (d < best) { best = d; bw = W; } }
#define MERGE_ADV()  { pp0 += (bw == 0); pp1 += (bw == 1); pp2 += (bw == 2); pp3 += (bw == 3); \
                       pp4 += (bw == 4); pp5 += (bw == 5); pp6 += (bw == 6); pp7 += (bw == 7); }

// K2: fused scan, LDS-staged candidates, Q=2/lane. blockIdx.z = mode (0=align
// on XP, 1=knn on YrP). Merge partials ALIAS the candidate stage (scan reads
// finish before the barrier) -> LDS stays 64KB -> 2 blocks/CU. Epilogue
// gathers hit the L2-resident global buffers instead of LDS.
__global__ __launch_bounds__(512, 4) void k_scan(const float* __restrict__ Xh,
                                                 const float4* __restrict__ XP,
                                                 const float4* __restrict__ YrP,
                                                 const float* __restrict__ dl,
                                                 float* __restrict__ acc,
                                                 unsigned* __restrict__ doneCnt,
                                                 float* __restrict__ out) {
    __shared__ float4 lsbuf[NPAD];                 // 64 KB: candidates, then merge partials
    float* mdp = (float*)lsbuf;
    int tid = threadIdx.x, wave = tid >> 6, lane = tid & 63;
    int qg = blockIdx.x, b = blockIdx.y, mode = blockIdx.z;
    int q0 = qg * QG + lane, q1 = q0 + 64;

    const float4* cbG = (mode == 0 ? XP : YrP) + (size_t)b * NPAD;
#pragma unroll
    for (int i = 0; i < NPAD / 512; ++i) lsbuf[tid + i * 512] = cbG[tid + i * 512];

    float qx0, qy0, qz0, qx1, qy1, qz1;
    if (mode == 0) {
        size_t a0 = ((size_t)b * NN + q0) * 3;
        size_t a1 = ((size_t)b * NN + q1) * 3;
        qx0 = Xh[a0 + 0]; qy0 = Xh[a0 + 1]; qz0 = Xh[a0 + 2];
        qx1 = Xh[a1 + 0]; qy1 = Xh[a1 + 1]; qz1 = Xh[a1 + 2];
    } else {
        float4 p0 = cbG[q0], p1 = cbG[q1];
        qx0 = p0.x; qy0 = p0.y; qz0 = p0.z;
        qx1 = p1.x; qy1 = p1.y; qz1 = p1.z;
    }
    __syncthreads();

    float x0 = INFF, x1 = INFF, x2 = INFF, x3 = INFF, x4 = INFF;
    float y0 = INFF, y1 = INFF, y2 = INFF, y3 = INFF, y4 = INFF;
    int tc = wave * CH;
    if (mode == 0) {
        scanLDS2<false, false>(lsbuf, tc,
                               -2.f * qx0, -2.f * qy0, -2.f * qz0, 0,
                               -2.f * qx1, -2.f * qy1, -2.f * qz1, 0,
                               x0, x1, x2, x3, x4, y0, y1, y2, y3, y4);
    } else if (wave == (qg >> 2)) {                // chunk containing this block's queries
        scanLDS2<true, true>(lsbuf, tc,
                             -2.f * qx0, -2.f * qy0, -2.f * qz0, q0,
                             -2.f * qx1, -2.f * qy1, -2.f * qz1, q1,
                             x0, x1, x2, x3, x4, y0, y1, y2, y3, y4);
    } else {
        scanLDS2<false, true>(lsbuf, tc,
                              -2.f * qx0, -2.f * qy0, -2.f * qz0, q0,
                              -2.f * qx1, -2.f * qy1, -2.f * qz1, q1,
                              x0, x1, x2, x3, x4, y0, y1, y2, y3, y4);
    }
    __syncthreads();                               // all scan reads of lsbuf done

    float* m0 = &mdp[(wave * QG + lane) * 6];
    m0[0] = x0; m0[1] = x1; m0[2] = x2; m0[3] = x3; m0[4] = x4; m0[5] = INFF;
    float* m1 = &mdp[(wave * QG + lane + 64) * 6];
    m1[0] = y0; m1[1] = y1; m1[2] = y2; m1[3] = y3; m1[4] = y4; m1[5] = INFF;
    __syncthreads();

    if (tid < QG) {
        int l = tid;
        int q = qg * QG + l;
        int pp0 = 0, pp1 = 0, pp2 = 0, pp3 = 0, pp4 = 0, pp5 = 0, pp6 = 0, pp7 = 0;
        if (mode == 0) {
            size_t a0 = ((size_t)b * NN + q) * 3;
            float qx = Xh[a0 + 0], qy = Xh[a0 + 1], qz = Xh[a0 + 2];
            float qn = fmaf(qx, qx, fmaf(qy, qy, qz * qz));
            float s = 0.f;
#pragma unroll
            for (int k = 0; k < KK; ++k) {
                float best = INFF; int bw = 0;
                MERGE_STEP(0) MERGE_STEP(1) MERGE_STEP(2) MERGE_STEP(3)
                MERGE_STEP(4) MERGE_STEP(5) MERGE_STEP(6) MERGE_STEP(7)
                s += fmaxf(best + qn, 0.f);
                MERGE_ADV()
            }
            s = waveReduceSum(s);
            if ((l & 63) == 0) atomicAdd(&acc[ACC_ALIGN], s);
        } else {
            int si[KK];
#pragma unroll
            for (int k = 0; k < KK; ++k) {
                float best = INFF; int bw = 0;
                MERGE_STEP(0) MERGE_STEP(1) MERGE_STEP(2) MERGE_STEP(3)
                MERGE_STEP(4) MERGE_STEP(5) MERGE_STEP(6) MERGE_STEP(7)
                si[k] = (int)(__float_as_uint(best) & 0xFFFu);
                MERGE_ADV()
            }
            float4 qp = cbG[q];
            const float* xh = Xh + (size_t)b * NN * 3;
            const float* dlb = dl + (size_t)b * NN * 3;
            float xnx = xh[q * 3 + 0], xny = xh[q * 3 + 1], xnz = xh[q * 3 + 2];
            float dnx = dlb[q * 3 + 0], dny = dlb[q * 3 + 1], dnz = dlb[q * 3 + 2];

            float def = 0.f, sx = 0.f, sy = 0.f, sz = 0.f;
#pragma unroll
            for (int k = 0; k < KK; ++k) {
                int n = si[k];
                float4 yj = cbG[n];                // L2-resident gather
                float ex = (xh[n * 3 + 0] - xnx) - (yj.x - qp.x);
                float ey = (xh[n * 3 + 1] - xny) - (yj.y - qp.y);
                float ez = (xh[n * 3 + 2] - xnz) - (yj.z - qp.z);
                def += ex * ex + ey * ey + ez * ez;
                sx += dlb[n * 3 + 0]; sy += dlb[n * 3 + 1]; sz += dlb[n * 3 + 2];
            }
            float lx = dnx - sx / 5.f, ly = dny - sy / 5.f, lz = dnz - sz / 5.f;
            float lap = lx * lx + ly * ly + lz * lz;

            def = waveReduceSum(def);
            lap = waveReduceSum(lap);
            if ((l & 63) == 0) {
                atomicAdd(&acc[ACC_DEFORM], def);
                atomicAdd(&acc[ACC_LAP], lap);
            }
        }
    }
    __syncthreads();
    if (tid == 0) {
        __threadfence();
        unsigned t = __hip_atomic_fetch_add(doneCnt, 1u, __ATOMIC_ACQ_REL,
                                            __HIP_MEMORY_SCOPE_AGENT);
        if (t == SCAN_BLOCKS - 1) finalize(acc, out);
    }
}

extern "C" void kernel_launch(void* const* d_in, const int* in_sizes, int n_in,
                              void* d_out, int out_size, void* d_ws, size_t ws_size,
                              hipStream_t stream) {
    const float* Y  = (const float*)d_in[0];
    const float* X  = (const float*)d_in[1];
    const float* Rp = (const float*)d_in[2];
    const float* tp = (const float*)d_in[3];
    const float* Rg = (const float*)d_in[4];
    const float* tg = (const float*)d_in[5];
    const float* Xh = (const float*)d_in[6];
    const float* dl = (const float*)d_in[7];
    float* out = (float*)d_out;

    float*    acc     = (float*)d_ws;                            // 14 floats
    unsigned* doneCnt = (unsigned*)((char*)d_ws + 64);
    float4*   YrP     = (float4*)((char*)d_ws + 512);            // 512 KB
    float4*   XP      = YrP + (size_t)BB * NPAD;                 // 512 KB

    hipMemsetAsync(d_ws, 0, 512, stream);
    hipLaunchKernelGGL(k_prep, dim3(BB * NN / 256), dim3(256), 0, stream,
                       Y, X, Rp, tp, Rg, tg, dl, YrP, XP, acc);
    hipLaunchKernelGGL(k_scan, dim3(NN / QG, BB, 2), dim3(512), 0, stream,
                       Xh, XP, YrP, dl, acc, doneCnt, out);
}